// Round 4
// baseline (506.441 us; speedup 1.0000x reference)
//
#include <hip/hip_runtime.h>
#include <math.h>

// Problem constants
#define N_TOKENS  16384
#define D_MODEL   4096
#define N_EXPERTS 64
#define CAPACITY  308          // ceil(1.2 * 16384 / 64)
#define BUCKET_CAP 1024
#define CAP_SLICES 4           // blocks per expert in capacity_kernel

// GEMM config: MFMA 16x16x32 bf16, exact 3-way split / 6-product fp32 emulation.
// Block = 128 tokens x 64 experts, 4 waves; wave = 32 tokens (2 m-subtiles of 16)
// so each B fragment read from LDS feeds 2x the MFMA (LDS-BW was the binding
// resource at 64-token blocks). Split-K NK=4, K-tile 64.
#define NK     4
#define KSPLIT (D_MODEL / NK)   // 1024
#define KTILE  64
#define NITER  (KSPLIT / KTILE) // 16

typedef __attribute__((ext_vector_type(8))) short bf16x8;
typedef __attribute__((ext_vector_type(4))) float f32x4;
typedef __attribute__((ext_vector_type(4))) unsigned int u32x4;

__device__ __forceinline__ unsigned short bf16_rne(float f) {
    unsigned u = __float_as_uint(f);
    u += 0x7fffu + ((u >> 16) & 1u);
    return (unsigned short)(u >> 16);
}
__device__ __forceinline__ float bf16_to_f32(unsigned short h) {
    return __uint_as_float(((unsigned)h) << 16);
}
// Exact 3-way RNE split: f == hi + mid + lo (fp32 24-bit mantissa -> 8+8+8).
__device__ __forceinline__ void split3(float f, unsigned short& h,
                                       unsigned short& m, unsigned short& l) {
    h = bf16_rne(f);
    float r1 = f - bf16_to_f32(h);   // exact, <= 16 significant bits
    m = bf16_rne(r1);
    float r2 = r1 - bf16_to_f32(m);  // exact, <= 8 significant bits
    l = bf16_rne(r2);                // exact
}

// Packed RNE f32->bf16 pair: low16 = cvt(a), high16 = cvt(b). Bit-identical to
// bf16_rne for all non-denormal results (gfx950 default round mode = RNE).
__device__ __forceinline__ unsigned cvt_pk_bf16(float a, float b) {
    unsigned r;
    asm("v_cvt_pk_bf16_f32 %0, %1, %2" : "=v"(r) : "v"(a), "v"(b));
    return r;
}
// Pair-wise 3-way split, packed output (elem0 in low16 of each word).
__device__ __forceinline__ void split3_pk(float f0, float f1,
                                          unsigned& hp, unsigned& mp, unsigned& lp) {
    hp = cvt_pk_bf16(f0, f1);
    float h0 = __uint_as_float(hp << 16);
    float h1 = __uint_as_float(hp & 0xffff0000u);
    float r0 = f0 - h0, r1 = f1 - h1;        // exact
    mp = cvt_pk_bf16(r0, r1);
    float m0 = __uint_as_float(mp << 16);
    float m1 = __uint_as_float(mp & 0xffff0000u);
    lp = cvt_pk_bf16(r0 - m0, r1 - m1);      // exact residual
}

__device__ __forceinline__ void glds16(const void* g, void* l) {
    // width=16 async global->LDS; LDS dest is wave-uniform base + lane*16
    __builtin_amdgcn_global_load_lds(
        (const __attribute__((address_space(1))) void*)g,
        (__attribute__((address_space(3))) void*)l, 16, 0, 0);
}

// ---- split W once: W[64][4096] fp32 -> whi/wmid/wlo bf16 ----
__global__ __launch_bounds__(256) void wsplit_kernel(
    const float* __restrict__ W,
    unsigned short* __restrict__ whi, unsigned short* __restrict__ wmid,
    unsigned short* __restrict__ wlo)
{
    int i = (blockIdx.x * 256 + threadIdx.x) * 4;
    float4 w = *(const float4*)&W[i];
    float e[4] = {w.x, w.y, w.z, w.w};
    ushort4 h, m, l;
    unsigned short* hp = &h.x; unsigned short* mp = &m.x; unsigned short* lp = &l.x;
    #pragma unroll
    for (int j = 0; j < 4; j++) split3(e[j], hp[j], mp[j], lp[j]);
    *(ushort4*)&whi[i]  = h;
    *(ushort4*)&wmid[i] = m;
    *(ushort4*)&wlo[i]  = l;
}

// ---- main GEMM: x[16384][4096] @ W^T -> part[NK][16384][64] ----
// LDS layouts (16B-chunk granularity, chunk c of row r stored at slot c^(r&7)):
//   xs : [128 rows][16 chunks] fp32, row = token          (32 KB)
//   bs*: [ 64 rows][ 8 chunks] bf16, row = expert         (3 x 8 KB)
// global_load_lds writes linearly (base + lane*16B), so the XOR is applied to
// the per-lane GLOBAL source chunk; ds_read applies the same XOR (m173 rule).
__global__ __launch_bounds__(256, 2) void gemm_kernel(
    const float* __restrict__ x,
    const unsigned short* __restrict__ whi,
    const unsigned short* __restrict__ wmid,
    const unsigned short* __restrict__ wlo,
    float* __restrict__ part)
{
    __shared__ float          xs[128 * 64];    // 32 KB
    __shared__ unsigned short bsh[64 * 64];    // 8 KB
    __shared__ unsigned short bsm[64 * 64];    // 8 KB
    __shared__ unsigned short bsl[64 * 64];    // 8 KB

    const int tid   = threadIdx.x;
    const int lane  = tid & 63;
    const int wv    = tid >> 6;
    const int tg    = blockIdx.x & 127;
    const int nk    = blockIdx.x >> 7;
    const int tbase = tg * 128;
    const int kbase = nk * KSPLIT;

    // staging lane geometry
    //  x  instr i (0..31): rows 4i..4i+3; lane -> row = 4i+(lane>>4),
    //     src chunk = (lane&15) ^ (row&7)
    //  B  instr j (0..7):  rows 8j..8j+7; lane -> row = 8j+(lane>>3),
    //     src chunk = (lane&7) ^ (lane>>3)
    const int xsub = lane >> 4;
    const int brow = lane >> 3;
    const int bcs  = (lane & 7) ^ brow;

    // MFMA fragment indices (A: m=lane&15, k=(lane>>4)*8+j; C/D: row=akq*4+r, col=lane&15)
    const int arow = lane & 15;
    const int akq  = lane >> 4;
    const int r7   = arow & 7;

    f32x4 acc[4][2];
    #pragma unroll
    for (int nt = 0; nt < 4; nt++)
        #pragma unroll
        for (int m2 = 0; m2 < 2; m2++)
            #pragma unroll
            for (int r = 0; r < 4; r++) acc[nt][m2][r] = 0.f;

    for (int t = 0; t < NITER; t++) {
        const int kc = t * KTILE;

        // ---- stage x tile: 32 glds, wave wv issues i = wv, wv+4, ..., wv+28
        #pragma unroll
        for (int m = 0; m < 8; m++) {
            int i   = wv + 4 * m;
            int row = 4 * i + xsub;
            int cs  = (lane & 15) ^ (row & 7);
            glds16(&x[(size_t)(tbase + row) * D_MODEL + kbase + kc + cs * 4],
                   &xs[i * 256]);
        }
        // ---- stage B tiles: 8 glds per array, wave wv issues j = wv, wv+4
        #pragma unroll
        for (int m = 0; m < 2; m++) {
            int j = wv + 4 * m;
            size_t soff = (size_t)(8 * j + brow) * D_MODEL + kbase + kc + bcs * 8;
            glds16(&whi [soff], &bsh[j * 512]);
            glds16(&wmid[soff], &bsm[j * 512]);
            glds16(&wlo [soff], &bsl[j * 512]);
        }
        __syncthreads();   // drains vmcnt -> staging visible to all waves

        // ---- compute: 2 k-steps of 32, 2 m-subtiles, 4 n-tiles, 6 products ----
        #pragma unroll
        for (int s = 0; s < 2; s++) {
            const int c0 = (s * 8 + akq * 2)     ^ r7;
            const int c1 = (s * 8 + akq * 2 + 1) ^ r7;
            unsigned ah[2][4], am[2][4], al[2][4];
            #pragma unroll
            for (int m2 = 0; m2 < 2; m2++) {
                const float* xrow = &xs[(wv * 32 + m2 * 16 + arow) * 64];
                float4 v0 = *(const float4*)&xrow[c0 * 4];
                float4 v1 = *(const float4*)&xrow[c1 * 4];
                split3_pk(v0.x, v0.y, ah[m2][0], am[m2][0], al[m2][0]);
                split3_pk(v0.z, v0.w, ah[m2][1], am[m2][1], al[m2][1]);
                split3_pk(v1.x, v1.y, ah[m2][2], am[m2][2], al[m2][2]);
                split3_pk(v1.z, v1.w, ah[m2][3], am[m2][3], al[m2][3]);
            }
            const int cb = (s * 4 + akq) ^ r7;
            #pragma unroll
            for (int nt = 0; nt < 4; nt++) {
                int boff = (nt * 16 + arow) * 64 + cb * 8;
                bf16x8 bh = *(const bf16x8*)&bsh[boff];
                bf16x8 bm = *(const bf16x8*)&bsm[boff];
                bf16x8 bl = *(const bf16x8*)&bsl[boff];
                #pragma unroll
                for (int m2 = 0; m2 < 2; m2++) {
                    union { u32x4 u; bf16x8 v; } Ah, Am, Al;
                    Ah.u = (u32x4){ah[m2][0], ah[m2][1], ah[m2][2], ah[m2][3]};
                    Am.u = (u32x4){am[m2][0], am[m2][1], am[m2][2], am[m2][3]};
                    Al.u = (u32x4){al[m2][0], al[m2][1], al[m2][2], al[m2][3]};
                    // magnitude-ordered: 1, 2^-8, 2^-8, 2^-16, 2^-16, 2^-16
                    acc[nt][m2] = __builtin_amdgcn_mfma_f32_16x16x32_bf16(Ah.v, bh, acc[nt][m2], 0, 0, 0);
                    acc[nt][m2] = __builtin_amdgcn_mfma_f32_16x16x32_bf16(Ah.v, bm, acc[nt][m2], 0, 0, 0);
                    acc[nt][m2] = __builtin_amdgcn_mfma_f32_16x16x32_bf16(Am.v, bh, acc[nt][m2], 0, 0, 0);
                    acc[nt][m2] = __builtin_amdgcn_mfma_f32_16x16x32_bf16(Ah.v, bl, acc[nt][m2], 0, 0, 0);
                    acc[nt][m2] = __builtin_amdgcn_mfma_f32_16x16x32_bf16(Am.v, bm, acc[nt][m2], 0, 0, 0);
                    acc[nt][m2] = __builtin_amdgcn_mfma_f32_16x16x32_bf16(Al.v, bh, acc[nt][m2], 0, 0, 0);
                }
            }
        }
        __syncthreads();   // all reads done before next tile overwrites LDS
    }

    // ---- write partials: token = tbase + wv*32 + m2*16 + akq*4 + r, expert = nt*16 + arow
    #pragma unroll
    for (int nt = 0; nt < 4; nt++)
        #pragma unroll
        for (int m2 = 0; m2 < 2; m2++)
            #pragma unroll
            for (int r = 0; r < 4; r++) {
                int tok = tbase + wv * 32 + m2 * 16 + akq * 4 + r;
                part[((size_t)nk * N_TOKENS + tok) * N_EXPERTS + nt * 16 + arow] = acc[nt][m2][r];
            }
}

// Combine partials + bias, softmax, top-2, bucket scatter, importance.
__global__ __launch_bounds__(256) void topk_kernel(
    const float* __restrict__ part, const float* __restrict__ b,
    float* __restrict__ out_ids, float* __restrict__ out_gates,
    int* __restrict__ cnt, float* __restrict__ imp,
    float2* __restrict__ bucket, int bucket_cap,
    float* __restrict__ out_mask)
{
    __shared__ float imp_s[4][N_EXPERTS];
    __shared__ float res_g[4][16];
    __shared__ int   res_i[4][16];
    const int tid  = threadIdx.x;
    const int wave = tid >> 6;
    const int lane = tid & 63;
    const int tok0 = blockIdx.x * 32 + wave * 8;
    float impacc = 0.f;

    for (int j = 0; j < 8; j++) {
        int tok = tok0 + j;
        float v = b[lane];
        #pragma unroll
        for (int k = 0; k < NK; k++)
            v += part[((size_t)k * N_TOKENS + tok) * N_EXPERTS + lane];

        float m = v;
        #pragma unroll
        for (int s = 32; s > 0; s >>= 1) m = fmaxf(m, __shfl_xor(m, s));
        float p = expf(v - m);
        float sum = p;
        #pragma unroll
        for (int s = 32; s > 0; s >>= 1) sum += __shfl_xor(sum, s);
        float prob = p / sum;
        impacc += prob;

        float bp = prob; int bi = lane;
        #pragma unroll
        for (int s = 32; s > 0; s >>= 1) {
            float op = __shfl_xor(bp, s); int oi = __shfl_xor(bi, s);
            if (op > bp || (op == bp && oi < bi)) { bp = op; bi = oi; }
        }
        float p2 = (lane == bi) ? -1.f : prob;
        float bp2 = p2; int bi2 = lane;
        #pragma unroll
        for (int s = 32; s > 0; s >>= 1) {
            float op = __shfl_xor(bp2, s); int oi = __shfl_xor(bi2, s);
            if (op > bp2 || (op == bp2 && oi < bi2)) { bp2 = op; bi2 = oi; }
        }

        if (lane == 0) {
            res_g[wave][j * 2]     = bp;  res_i[wave][j * 2]     = bi;
            res_g[wave][j * 2 + 1] = bp2; res_i[wave][j * 2 + 1] = bi2;
        }
    }

    __builtin_amdgcn_wave_barrier();
    if (lane < 16) {
        int tok  = tok0 + (lane >> 1);
        int slot = tok * 2 + (lane & 1);
        float g  = res_g[wave][lane];
        int   id = res_i[wave][lane];
        out_ids[slot]   = (float)id;
        out_gates[slot] = g;
        int pos = atomicAdd(&cnt[id], 1);
        if (pos < bucket_cap)
            bucket[id * bucket_cap + pos] = make_float2(g, __int_as_float(slot));
        else
            out_mask[slot] = 0.f;
    }

    imp_s[wave][lane] = impacc;
    __syncthreads();
    if (wave == 0) {
        float s = imp_s[0][lane] + imp_s[1][lane] + imp_s[2][lane] + imp_s[3][lane];
        atomicAdd(&imp[lane], s);
    }
}

// CAP_SLICES blocks per expert: exact lexsort rank via O(n^2) comparison,
// batched float4/int4 broadcast reads from LDS (latency-hiding, conflict-free).
__global__ __launch_bounds__(256) void capacity_kernel(
    const int* __restrict__ cnt, const float2* __restrict__ bucket,
    float* __restrict__ out_mask, int bucket_cap)
{
    __shared__ __align__(16) float g_s[BUCKET_CAP];
    __shared__ __align__(16) int   i_s[BUCKET_CAP];
    const int e     = blockIdx.x / CAP_SLICES;
    const int slice = blockIdx.x % CAP_SLICES;
    int n = cnt[e];
    if (n > bucket_cap) n = bucket_cap;

    for (int i = threadIdx.x; i < n; i += 256) {
        float2 r = bucket[e * bucket_cap + i];
        g_s[i] = r.x;
        i_s[i] = __float_as_int(r.y);
    }
    __syncthreads();

    const int chunk = (n + CAP_SLICES - 1) / CAP_SLICES;   // <= 256
    const int i = slice * chunk + threadIdx.x;
    if (threadIdx.x < chunk && i < n) {
        const float gi = g_s[i];
        const int   ii = i_s[i];
        int rank = 0;
        const int n4 = n & ~3;
        for (int j = 0; j < n4; j += 4) {
            float4 g = *(const float4*)&g_s[j];
            int4   d = *(const int4*)&i_s[j];
            rank += (g.x > gi || (g.x == gi && d.x < ii)) ? 1 : 0;
            rank += (g.y > gi || (g.y == gi && d.y < ii)) ? 1 : 0;
            rank += (g.z > gi || (g.z == gi && d.z < ii)) ? 1 : 0;
            rank += (g.w > gi || (g.w == gi && d.w < ii)) ? 1 : 0;
        }
        for (int j = n4; j < n; j++) {
            float gj = g_s[j]; int ij = i_s[j];
            rank += (gj > gi || (gj == gi && ij < ii)) ? 1 : 0;
        }
        out_mask[ii] = (rank < CAPACITY) ? 1.f : 0.f;
    }
}

__global__ void aux_kernel(const int* __restrict__ cnt,
                           const float* __restrict__ imp,
                           float* __restrict__ out_aux)
{
    int lane = threadIdx.x;
    float load = (float)min(cnt[lane], CAPACITY);
    float v = (float)N_EXPERTS * (imp[lane] / (float)N_TOKENS) * (load / (float)N_TOKENS);
    #pragma unroll
    for (int s = 32; s > 0; s >>= 1) v += __shfl_xor(v, s);
    if (lane == 0) out_aux[0] = v;
}

extern "C" void kernel_launch(void* const* d_in, const int* in_sizes, int n_in,
                              void* d_out, int out_size, void* d_ws, size_t ws_size,
                              hipStream_t stream) {
    const float* x = (const float*)d_in[0];
    const float* W = (const float*)d_in[1];
    const float* b = (const float*)d_in[2];

    float* out       = (float*)d_out;
    float* out_ids   = out;
    float* out_gates = out + 32768;
    float* out_aux   = out + 65536;
    float* out_mask  = out + 65537;

    // ws: [0,256) cnt | [256,512) imp | part NK*4MB | whi/wmid/wlo 3*512KB | buckets
    const size_t partN = (size_t)N_TOKENS * N_EXPERTS * sizeof(float);          // 4 MB
    const size_t wN    = (size_t)N_EXPERTS * D_MODEL * sizeof(unsigned short);  // 512 KB

    int*            cnt    = (int*)d_ws;
    float*          imp    = (float*)((char*)d_ws + 256);
    float*          part   = (float*)((char*)d_ws + 512);
    unsigned short* whi    = (unsigned short*)((char*)d_ws + 512 + NK * partN);
    unsigned short* wmid   = (unsigned short*)((char*)d_ws + 512 + NK * partN + wN);
    unsigned short* wlo    = (unsigned short*)((char*)d_ws + 512 + NK * partN + 2 * wN);
    float2*         bucket = (float2*)((char*)d_ws + 512 + NK * partN + 3 * wN);

    size_t used = 512 + NK * partN + 3 * wN;
    int bucket_cap = (ws_size > used) ? (int)((ws_size - used) / (N_EXPERTS * sizeof(float2))) : 0;
    if (bucket_cap > BUCKET_CAP) bucket_cap = BUCKET_CAP;

    hipMemsetAsync(d_ws, 0, 512, stream);

    wsplit_kernel<<<(N_EXPERTS * D_MODEL) / (256 * 4), 256, 0, stream>>>(W, whi, wmid, wlo);
    gemm_kernel<<<128 * NK, 256, 0, stream>>>(x, whi, wmid, wlo, part);
    topk_kernel<<<512, 256, 0, stream>>>(part, b, out_ids, out_gates,
                                         cnt, imp, bucket, bucket_cap, out_mask);
    capacity_kernel<<<N_EXPERTS * CAP_SLICES, 256, 0, stream>>>(cnt, bucket, out_mask, bucket_cap);
    aux_kernel<<<1, 64, 0, stream>>>(cnt, imp, out_aux);
}

// Round 5
// 502.992 us; speedup vs baseline: 1.0069x; 1.0069x over previous
//
#include <hip/hip_runtime.h>
#include <math.h>

// Problem constants
#define N_TOKENS  16384
#define D_MODEL   4096
#define N_EXPERTS 64
#define CAPACITY  308          // ceil(1.2 * 16384 / 64)
#define BUCKET_CAP 1024
#define CAP_SLICES 4           // blocks per expert in capacity_kernel

// GEMM config: MFMA 16x16x32 bf16, exact 3-way split / 6-product fp32 emulation.
// Block = 64 tokens x 64 experts, 4 waves, split-K NK=4, K-tile 64.
// DOUBLE-BUFFERED pipeline (T3 minimum 2-phase): issue next tile's
// global_load_lds BEFORE computing the current tile, one barrier per tile.
// The barrier's vmcnt(0) drain then lands after a full compute phase, so HBM
// latency is hidden instead of serially added (R4 showed throughput resources
// are not the limit; the stage->drain->compute serialization is).
#define NK     4
#define KSPLIT (D_MODEL / NK)   // 1024
#define KTILE  64
#define NITER  (KSPLIT / KTILE) // 16

typedef __attribute__((ext_vector_type(8))) short bf16x8;
typedef __attribute__((ext_vector_type(4))) float f32x4;
typedef __attribute__((ext_vector_type(4))) unsigned int u32x4;

__device__ __forceinline__ unsigned short bf16_rne(float f) {
    unsigned u = __float_as_uint(f);
    u += 0x7fffu + ((u >> 16) & 1u);
    return (unsigned short)(u >> 16);
}
__device__ __forceinline__ float bf16_to_f32(unsigned short h) {
    return __uint_as_float(((unsigned)h) << 16);
}
// Exact 3-way RNE split: f == hi + mid + lo (fp32 24-bit mantissa -> 8+8+8).
__device__ __forceinline__ void split3(float f, unsigned short& h,
                                       unsigned short& m, unsigned short& l) {
    h = bf16_rne(f);
    float r1 = f - bf16_to_f32(h);   // exact, <= 16 significant bits
    m = bf16_rne(r1);
    float r2 = r1 - bf16_to_f32(m);  // exact, <= 8 significant bits
    l = bf16_rne(r2);                // exact
}

// Packed RNE f32->bf16 pair: low16 = cvt(a), high16 = cvt(b). Bit-identical to
// bf16_rne for all non-denormal results (gfx950 default round mode = RNE).
__device__ __forceinline__ unsigned cvt_pk_bf16(float a, float b) {
    unsigned r;
    asm("v_cvt_pk_bf16_f32 %0, %1, %2" : "=v"(r) : "v"(a), "v"(b));
    return r;
}
// Pair-wise 3-way split, packed output (elem0 in low16 of each word).
__device__ __forceinline__ void split3_pk(float f0, float f1,
                                          unsigned& hp, unsigned& mp, unsigned& lp) {
    hp = cvt_pk_bf16(f0, f1);
    float h0 = __uint_as_float(hp << 16);
    float h1 = __uint_as_float(hp & 0xffff0000u);
    float r0 = f0 - h0, r1 = f1 - h1;        // exact
    mp = cvt_pk_bf16(r0, r1);
    float m0 = __uint_as_float(mp << 16);
    float m1 = __uint_as_float(mp & 0xffff0000u);
    lp = cvt_pk_bf16(r0 - m0, r1 - m1);      // exact residual
}

__device__ __forceinline__ void glds16(const void* g, void* l) {
    // width=16 async global->LDS; LDS dest is wave-uniform base + lane*16
    __builtin_amdgcn_global_load_lds(
        (const __attribute__((address_space(1))) void*)g,
        (__attribute__((address_space(3))) void*)l, 16, 0, 0);
}

// ---- split W once: W[64][4096] fp32 -> whi/wmid/wlo bf16 ----
__global__ __launch_bounds__(256) void wsplit_kernel(
    const float* __restrict__ W,
    unsigned short* __restrict__ whi, unsigned short* __restrict__ wmid,
    unsigned short* __restrict__ wlo)
{
    int i = (blockIdx.x * 256 + threadIdx.x) * 4;
    float4 w = *(const float4*)&W[i];
    float e[4] = {w.x, w.y, w.z, w.w};
    ushort4 h, m, l;
    unsigned short* hp = &h.x; unsigned short* mp = &m.x; unsigned short* lp = &l.x;
    #pragma unroll
    for (int j = 0; j < 4; j++) split3(e[j], hp[j], mp[j], lp[j]);
    *(ushort4*)&whi[i]  = h;
    *(ushort4*)&wmid[i] = m;
    *(ushort4*)&wlo[i]  = l;
}

// ---- main GEMM: x[16384][4096] @ W^T -> part[NK][16384][64] ----
// LDS layouts (16B-chunk granularity, chunk c of row r stored at slot c^(r&7)):
//   xs : [2][64 rows][16 chunks] fp32, row = token        (2 x 16 KB)
//   bs*: [2][64 rows][ 8 chunks] bf16, row = expert       (3 x 2 x 8 KB)
// Total 80 KB -> 2 blocks/CU. global_load_lds writes linearly, so the XOR
// is applied to the per-lane GLOBAL source chunk; ds_read applies the same
// XOR (both-sides-or-neither rule).
__global__ __launch_bounds__(256, 2) void gemm_kernel(
    const float* __restrict__ x,
    const unsigned short* __restrict__ whi,
    const unsigned short* __restrict__ wmid,
    const unsigned short* __restrict__ wlo,
    float* __restrict__ part)
{
    __shared__ float          xs[2][64 * 64];    // 2 x 16 KB
    __shared__ unsigned short bsh[2][64 * 64];   // 2 x 8 KB
    __shared__ unsigned short bsm[2][64 * 64];   // 2 x 8 KB
    __shared__ unsigned short bsl[2][64 * 64];   // 2 x 8 KB

    const int tid   = threadIdx.x;
    const int lane  = tid & 63;
    const int wv    = tid >> 6;
    const int tg    = blockIdx.x & 255;
    const int nk    = blockIdx.x >> 8;
    const int tbase = tg * 64;
    const int kbase = nk * KSPLIT;

    // staging lane geometry
    //  x  instr i (0..15): rows 4i..4i+3; lane -> row = 4i+(lane>>4),
    //     src chunk = (lane&15) ^ (row&7)
    //  B  instr j (0..7):  rows 8j..8j+7; lane -> row = 8j+(lane>>3),
    //     src chunk = (lane&7) ^ (lane>>3)
    const int xsub = lane >> 4;
    const int brow = lane >> 3;
    const int bcs  = (lane & 7) ^ brow;

    // MFMA fragment indices (A: m=lane&15, k=(lane>>4)*8+j; C/D: row=akq*4+r, col=lane&15)
    const int arow = lane & 15;
    const int akq  = lane >> 4;
    const int r7   = arow & 7;

    auto stage = [&](int buf, int kc) {
        #pragma unroll
        for (int m = 0; m < 4; m++) {
            int i   = wv + 4 * m;
            int row = 4 * i + xsub;
            int cs  = (lane & 15) ^ (row & 7);
            glds16(&x[(size_t)(tbase + row) * D_MODEL + kbase + kc + cs * 4],
                   &xs[buf][i * 256]);
        }
        #pragma unroll
        for (int m = 0; m < 2; m++) {
            int j = wv + 4 * m;
            size_t soff = (size_t)(8 * j + brow) * D_MODEL + kbase + kc + bcs * 8;
            glds16(&whi [soff], &bsh[buf][j * 512]);
            glds16(&wmid[soff], &bsm[buf][j * 512]);
            glds16(&wlo [soff], &bsl[buf][j * 512]);
        }
    };

    f32x4 acc[4];
    #pragma unroll
    for (int nt = 0; nt < 4; nt++)
        #pragma unroll
        for (int r = 0; r < 4; r++) acc[nt][r] = 0.f;

    // prologue: stage tile 0, wait for it
    stage(0, 0);
    __syncthreads();

    for (int t = 0; t < NITER; t++) {
        const int cur = t & 1;

        // ---- issue next tile's staging into the other buffer FIRST; these
        // loads stay in flight under the whole compute phase below and are
        // drained by the barrier's vmcnt(0) at the end of this iteration.
        if (t + 1 < NITER) stage(cur ^ 1, (t + 1) * KTILE);

        // ---- compute current tile: 2 k-steps of 32, 4 n-tiles, 6 products ----
        #pragma unroll
        for (int s = 0; s < 2; s++) {
            const float* xrow = &xs[cur][(wv * 16 + arow) * 64];
            const int c0 = (s * 8 + akq * 2)     ^ r7;
            const int c1 = (s * 8 + akq * 2 + 1) ^ r7;
            float4 v0 = *(const float4*)&xrow[c0 * 4];
            float4 v1 = *(const float4*)&xrow[c1 * 4];
            unsigned ah[4], am[4], al[4];
            split3_pk(v0.x, v0.y, ah[0], am[0], al[0]);
            split3_pk(v0.z, v0.w, ah[1], am[1], al[1]);
            split3_pk(v1.x, v1.y, ah[2], am[2], al[2]);
            split3_pk(v1.z, v1.w, ah[3], am[3], al[3]);
            union { u32x4 u; bf16x8 v; } Ah, Am, Al;
            Ah.u = (u32x4){ah[0], ah[1], ah[2], ah[3]};
            Am.u = (u32x4){am[0], am[1], am[2], am[3]};
            Al.u = (u32x4){al[0], al[1], al[2], al[3]};
            const int cb = (s * 4 + akq) ^ r7;
            #pragma unroll
            for (int nt = 0; nt < 4; nt++) {
                int boff = (nt * 16 + arow) * 64 + cb * 8;
                bf16x8 bh = *(const bf16x8*)&bsh[cur][boff];
                bf16x8 bm = *(const bf16x8*)&bsm[cur][boff];
                bf16x8 bl = *(const bf16x8*)&bsl[cur][boff];
                // magnitude-ordered: 1, 2^-8, 2^-8, 2^-16, 2^-16, 2^-16
                acc[nt] = __builtin_amdgcn_mfma_f32_16x16x32_bf16(Ah.v, bh, acc[nt], 0, 0, 0);
                acc[nt] = __builtin_amdgcn_mfma_f32_16x16x32_bf16(Ah.v, bm, acc[nt], 0, 0, 0);
                acc[nt] = __builtin_amdgcn_mfma_f32_16x16x32_bf16(Am.v, bh, acc[nt], 0, 0, 0);
                acc[nt] = __builtin_amdgcn_mfma_f32_16x16x32_bf16(Ah.v, bl, acc[nt], 0, 0, 0);
                acc[nt] = __builtin_amdgcn_mfma_f32_16x16x32_bf16(Am.v, bm, acc[nt], 0, 0, 0);
                acc[nt] = __builtin_amdgcn_mfma_f32_16x16x32_bf16(Al.v, bh, acc[nt], 0, 0, 0);
            }
        }

        // one barrier per tile: drains prefetch (vmcnt) + orders LDS reuse
        __syncthreads();
    }

    // ---- write partials: token = tbase + wv*16 + akq*4 + r, expert = nt*16 + arow
    #pragma unroll
    for (int nt = 0; nt < 4; nt++) {
        #pragma unroll
        for (int r = 0; r < 4; r++) {
            int tok = tbase + wv * 16 + akq * 4 + r;
            part[((size_t)nk * N_TOKENS + tok) * N_EXPERTS + nt * 16 + arow] = acc[nt][r];
        }
    }
}

// Combine partials + bias, softmax, top-2, bucket scatter, importance.
__global__ __launch_bounds__(256) void topk_kernel(
    const float* __restrict__ part, const float* __restrict__ b,
    float* __restrict__ out_ids, float* __restrict__ out_gates,
    int* __restrict__ cnt, float* __restrict__ imp,
    float2* __restrict__ bucket, int bucket_cap,
    float* __restrict__ out_mask)
{
    __shared__ float imp_s[4][N_EXPERTS];
    __shared__ float res_g[4][16];
    __shared__ int   res_i[4][16];
    const int tid  = threadIdx.x;
    const int wave = tid >> 6;
    const int lane = tid & 63;
    const int tok0 = blockIdx.x * 32 + wave * 8;
    float impacc = 0.f;

    for (int j = 0; j < 8; j++) {
        int tok = tok0 + j;
        float v = b[lane];
        #pragma unroll
        for (int k = 0; k < NK; k++)
            v += part[((size_t)k * N_TOKENS + tok) * N_EXPERTS + lane];

        float m = v;
        #pragma unroll
        for (int s = 32; s > 0; s >>= 1) m = fmaxf(m, __shfl_xor(m, s));
        float p = expf(v - m);
        float sum = p;
        #pragma unroll
        for (int s = 32; s > 0; s >>= 1) sum += __shfl_xor(sum, s);
        float prob = p / sum;
        impacc += prob;

        float bp = prob; int bi = lane;
        #pragma unroll
        for (int s = 32; s > 0; s >>= 1) {
            float op = __shfl_xor(bp, s); int oi = __shfl_xor(bi, s);
            if (op > bp || (op == bp && oi < bi)) { bp = op; bi = oi; }
        }
        float p2 = (lane == bi) ? -1.f : prob;
        float bp2 = p2; int bi2 = lane;
        #pragma unroll
        for (int s = 32; s > 0; s >>= 1) {
            float op = __shfl_xor(bp2, s); int oi = __shfl_xor(bi2, s);
            if (op > bp2 || (op == bp2 && oi < bi2)) { bp2 = op; bi2 = oi; }
        }

        if (lane == 0) {
            res_g[wave][j * 2]     = bp;  res_i[wave][j * 2]     = bi;
            res_g[wave][j * 2 + 1] = bp2; res_i[wave][j * 2 + 1] = bi2;
        }
    }

    __builtin_amdgcn_wave_barrier();
    if (lane < 16) {
        int tok  = tok0 + (lane >> 1);
        int slot = tok * 2 + (lane & 1);
        float g  = res_g[wave][lane];
        int   id = res_i[wave][lane];
        out_ids[slot]   = (float)id;
        out_gates[slot] = g;
        int pos = atomicAdd(&cnt[id], 1);
        if (pos < bucket_cap)
            bucket[id * bucket_cap + pos] = make_float2(g, __int_as_float(slot));
        else
            out_mask[slot] = 0.f;
    }

    imp_s[wave][lane] = impacc;
    __syncthreads();
    if (wave == 0) {
        float s = imp_s[0][lane] + imp_s[1][lane] + imp_s[2][lane] + imp_s[3][lane];
        atomicAdd(&imp[lane], s);
    }
}

// CAP_SLICES blocks per expert: exact lexsort rank via O(n^2) comparison,
// batched float4/int4 broadcast reads from LDS. One extra block (the last)
// computes the aux loss (independent of capacity output -> safe to co-run).
__global__ __launch_bounds__(256) void capacity_kernel(
    const int* __restrict__ cnt, const float2* __restrict__ bucket,
    float* __restrict__ out_mask, int bucket_cap,
    const float* __restrict__ imp, float* __restrict__ out_aux)
{
    __shared__ __align__(16) float g_s[BUCKET_CAP];
    __shared__ __align__(16) int   i_s[BUCKET_CAP];

    if (blockIdx.x == N_EXPERTS * CAP_SLICES) {
        // aux block: whole block takes this path (no barriers inside)
        int lane = threadIdx.x;
        if (lane < 64) {
            float load = (float)min(cnt[lane], CAPACITY);
            float v = (float)N_EXPERTS * (imp[lane] / (float)N_TOKENS) * (load / (float)N_TOKENS);
            #pragma unroll
            for (int s = 32; s > 0; s >>= 1) v += __shfl_xor(v, s);
            if (lane == 0) out_aux[0] = v;
        }
        return;
    }

    const int e     = blockIdx.x / CAP_SLICES;
    const int slice = blockIdx.x % CAP_SLICES;
    int n = cnt[e];
    if (n > bucket_cap) n = bucket_cap;

    for (int i = threadIdx.x; i < n; i += 256) {
        float2 r = bucket[e * bucket_cap + i];
        g_s[i] = r.x;
        i_s[i] = __float_as_int(r.y);
    }
    __syncthreads();

    const int chunk = (n + CAP_SLICES - 1) / CAP_SLICES;   // <= 256
    const int i = slice * chunk + threadIdx.x;
    if (threadIdx.x < chunk && i < n) {
        const float gi = g_s[i];
        const int   ii = i_s[i];
        int rank = 0;
        const int n4 = n & ~3;
        for (int j = 0; j < n4; j += 4) {
            float4 g = *(const float4*)&g_s[j];
            int4   d = *(const int4*)&i_s[j];
            rank += (g.x > gi || (g.x == gi && d.x < ii)) ? 1 : 0;
            rank += (g.y > gi || (g.y == gi && d.y < ii)) ? 1 : 0;
            rank += (g.z > gi || (g.z == gi && d.z < ii)) ? 1 : 0;
            rank += (g.w > gi || (g.w == gi && d.w < ii)) ? 1 : 0;
        }
        for (int j = n4; j < n; j++) {
            float gj = g_s[j]; int ij = i_s[j];
            rank += (gj > gi || (gj == gi && ij < ii)) ? 1 : 0;
        }
        out_mask[ii] = (rank < CAPACITY) ? 1.f : 0.f;
    }
}

extern "C" void kernel_launch(void* const* d_in, const int* in_sizes, int n_in,
                              void* d_out, int out_size, void* d_ws, size_t ws_size,
                              hipStream_t stream) {
    const float* x = (const float*)d_in[0];
    const float* W = (const float*)d_in[1];
    const float* b = (const float*)d_in[2];

    float* out       = (float*)d_out;
    float* out_ids   = out;
    float* out_gates = out + 32768;
    float* out_aux   = out + 65536;
    float* out_mask  = out + 65537;

    // ws: [0,256) cnt | [256,512) imp | part NK*4MB | whi/wmid/wlo 3*512KB | buckets
    const size_t partN = (size_t)N_TOKENS * N_EXPERTS * sizeof(float);          // 4 MB
    const size_t wN    = (size_t)N_EXPERTS * D_MODEL * sizeof(unsigned short);  // 512 KB

    int*            cnt    = (int*)d_ws;
    float*          imp    = (float*)((char*)d_ws + 256);
    float*          part   = (float*)((char*)d_ws + 512);
    unsigned short* whi    = (unsigned short*)((char*)d_ws + 512 + NK * partN);
    unsigned short* wmid   = (unsigned short*)((char*)d_ws + 512 + NK * partN + wN);
    unsigned short* wlo    = (unsigned short*)((char*)d_ws + 512 + NK * partN + 2 * wN);
    float2*         bucket = (float2*)((char*)d_ws + 512 + NK * partN + 3 * wN);

    size_t used = 512 + NK * partN + 3 * wN;
    int bucket_cap = (ws_size > used) ? (int)((ws_size - used) / (N_EXPERTS * sizeof(float2))) : 0;
    if (bucket_cap > BUCKET_CAP) bucket_cap = BUCKET_CAP;

    hipMemsetAsync(d_ws, 0, 512, stream);

    wsplit_kernel<<<(N_EXPERTS * D_MODEL) / (256 * 4), 256, 0, stream>>>(W, whi, wmid, wlo);
    gemm_kernel<<<256 * NK, 256, 0, stream>>>(x, whi, wmid, wlo, part);
    topk_kernel<<<512, 256, 0, stream>>>(part, b, out_ids, out_gates,
                                         cnt, imp, bucket, bucket_cap, out_mask);
    capacity_kernel<<<N_EXPERTS * CAP_SLICES + 1, 256, 0, stream>>>(
        cnt, bucket, out_mask, bucket_cap, imp, out_aux);
}